// Round 3
// baseline (208.548 us; speedup 1.0000x reference)
//
#include <hip/hip_runtime.h>
#include <hip/hip_bf16.h>
#include <math.h>

#define DIMC 512
#define NSEQ 1536
#define BATCH 4
#define NHEADS 8
#define HDIM 64
#define SSEG 512          // NSEQ/3
#define HIDDEN_DIM 1024
#define ALPHA_C 0.5f
#define EPS_C 1e-5f
#define NROWS (BATCH*NSEQ) // 6144
#define SHIFT_L2 8.65617025f    // 6.0 * log2(e): static softmax shift, base-2 units
#define HSHIFT_L2 4.328085125f  // (1-ALPHA)*SHIFT_L2, for seg1/seg2 C-init folding
#define QSCALE_L2 0.18033688f   // 0.125 * log2(e): folded into Q at GEMM epilogue

typedef __attribute__((ext_vector_type(8))) short bfrag8;      // 8 bf16
typedef __attribute__((ext_vector_type(8))) _Float16 hfrag8;   // 8 f16
typedef __attribute__((ext_vector_type(2))) __fp16 h2;         // cvt_pkrtz result type
typedef __attribute__((ext_vector_type(4))) float ffrag;       // 4 f32 acc
typedef float4 f4;

// Packed per-(b,h) fragment-contiguous layouts so attention loads are 1KB bursts:
//  Qp/Kp: [bh][96 key16blk][f<2][cl<16][qg<4][j<8]  bf16  (1024 elems / 16-token blk)
//  Vp:    [bh][48 key32blk][mg<4][cl<16][qg<4][j<8] f16   (2048 elems / 32-token blk)

__device__ __forceinline__ ushort f2bf(float v) {
    __hip_bfloat16 hb = __float2bfloat16(v);
    return *(ushort*)&hb;
}

// async global->LDS, 16B per lane; lds dest = wave-uniform base + lane*16
__device__ __forceinline__ void gl2lds16(const ushort* g, ushort* l) {
    __builtin_amdgcn_global_load_lds(
        (const __attribute__((address_space(1))) unsigned*)g,
        (__attribute__((address_space(3))) unsigned*)l, 16, 0, 0);
}

// ---------------- fused prep: weight transpose-converts + LN1 ---------------
__global__ __launch_bounds__(256)
void prep_kernel(const float* __restrict__ qkv_w, const float* __restrict__ fc1_w,
                 const float* __restrict__ fc2_w, ushort* __restrict__ qkv_wt,
                 ushort* __restrict__ fc1_wt, ushort* __restrict__ fc2_wt,
                 const float* __restrict__ x, const float* __restrict__ g,
                 const float* __restrict__ bvec, ushort* __restrict__ h_out)
{
    int bid = blockIdx.x;
    if (bid < 448) {
        __shared__ float tile[64][65];
        const float* W; ushort* Wt; int K, N, n0, k0;
        if (bid < 192)      { W = qkv_w; Wt = qkv_wt; K = 512;  N = 1536; int b = bid;       n0 = (b % 24) * 64; k0 = (b / 24) * 64; }
        else if (bid < 320) { W = fc1_w; Wt = fc1_wt; K = 512;  N = 1024; int b = bid - 192; n0 = (b % 16) * 64; k0 = (b / 16) * 64; }
        else                { W = fc2_w; Wt = fc2_wt; K = 1024; N = 512;  int b = bid - 320; n0 = (b % 8)  * 64; k0 = (b / 8)  * 64; }
        int tx = threadIdx.x & 63, ty = threadIdx.x >> 6;
        #pragma unroll
        for (int i = 0; i < 16; i++) {
            int r = i * 4 + ty;
            tile[r][tx] = W[(size_t)(k0 + r) * N + n0 + tx];
        }
        __syncthreads();
        #pragma unroll
        for (int i = 0; i < 16; i++) {
            int r = i * 4 + ty;
            Wt[(size_t)(n0 + r) * K + k0 + tx] = f2bf(tile[tx][r]);
        }
    } else {
        __shared__ float red[16];
        int row = bid - 448;
        int t = threadIdx.x;
        int lane = t & 63, w = t >> 6;
        const float* rp = x + (size_t)row * DIMC;
        float v0 = rp[t];
        float v1 = rp[t + 256];
        float s = v0 + v1;
        float s2 = v0 * v0 + v1 * v1;
        #pragma unroll
        for (int o = 32; o > 0; o >>= 1) {
            s  += __shfl_down(s,  o, 64);
            s2 += __shfl_down(s2, o, 64);
        }
        if (lane == 0) { red[w] = s; red[8 + w] = s2; }
        __syncthreads();
        if (t == 0) {
            float a = red[0] + red[1] + red[2] + red[3];
            float c = red[8] + red[9] + red[10] + red[11];
            red[0] = a; red[8] = c;
        }
        __syncthreads();
        float mean = red[0] * (1.0f / DIMC);
        float var  = red[8] * (1.0f / DIMC) - mean * mean;
        float rstd = rsqrtf(var + EPS_C);
        ushort* op = h_out + (size_t)row * DIMC;
        op[t]       = f2bf((v0 - mean) * rstd * g[t]       + bvec[t]);
        op[t + 256] = f2bf((v1 - mean) * rstd * g[t + 256] + bvec[t + 256]);
    }
}

// ---------------- LayerNorm: fp32 in -> bf16 out ----------------------------
__global__ __launch_bounds__(256)
void ln_kernel(const float* __restrict__ in, const float* __restrict__ g,
               const float* __restrict__ b, ushort* __restrict__ out)
{
    __shared__ float red[16];
    int row = blockIdx.x;
    int t = threadIdx.x;
    int lane = t & 63, w = t >> 6;
    const float* rp = in + (size_t)row * DIMC;
    float v0 = rp[t];
    float v1 = rp[t + 256];
    float s = v0 + v1;
    float s2 = v0 * v0 + v1 * v1;
    #pragma unroll
    for (int o = 32; o > 0; o >>= 1) {
        s  += __shfl_down(s,  o, 64);
        s2 += __shfl_down(s2, o, 64);
    }
    if (lane == 0) { red[w] = s; red[8 + w] = s2; }
    __syncthreads();
    if (t == 0) {
        float a = red[0] + red[1] + red[2] + red[3];
        float c = red[8] + red[9] + red[10] + red[11];
        red[0] = a; red[8] = c;
    }
    __syncthreads();
    float mean = red[0] * (1.0f / DIMC);
    float var  = red[8] * (1.0f / DIMC) - mean * mean;
    float rstd = rsqrtf(var + EPS_C);
    ushort* op = out + (size_t)row * DIMC;
    op[t]       = f2bf((v0 - mean) * rstd * g[t]       + b[t]);
    op[t + 256] = f2bf((v1 - mean) * rstd * g[t + 256] + b[t + 256]);
}

// ---------------- MFMA GEMM body (64x64): C = A @ Wt^T ----------------------
// EPI: 0 = +bias[col], store bf16 (QK: cols<512 pre-scaled)
//      1 = +bias[col], exact GELU, store bf16
//      2 = +bias[col] +resid(f32), store f32
//      3 = +bias[row], store f16 PACKED V layout (see header comment)
template <int EPI>
__device__ __forceinline__
void mgemm_body(const ushort* __restrict__ A, const ushort* __restrict__ Wt,
                const float* __restrict__ bias, const float* resid,
                void* out, int M, int K, int Nn, int bx, int by,
                ushort* As, ushort* Bs)   // each [2][2][64*32] = 16KB
{
    int tid = threadIdx.x;
    int lane = tid & 63, w = tid >> 6;
    int cl = lane & 15, qg = lane >> 4;
    int wm = w >> 1, wn = w & 1;
    int rowBase = by * 64, colBase = bx * 64;
    int sr = lane >> 2;
    int sb = (lane & 3) * 8;

    const ushort* agb = A  + (size_t)(rowBase + w * 16 + sr) * K + sb;
    const ushort* bgb = Wt + (size_t)(colBase + w * 16 + sr) * K + sb;

    ffrag acc[2][2];
    #pragma unroll
    for (int mi = 0; mi < 2; mi++)
        #pragma unroll
        for (int ni = 0; ni < 2; ni++)
            #pragma unroll
            for (int r = 0; r < 4; r++) acc[mi][ni][r] = 0.f;

    int niter = K >> 6;

    #pragma unroll
    for (int hf = 0; hf < 2; hf++) {
        gl2lds16(agb + hf * 32, As + (0 * 2 + hf) * 2048 + (w * 16) * 32);
        gl2lds16(bgb + hf * 32, Bs + (0 * 2 + hf) * 2048 + (w * 16) * 32);
    }
    __syncthreads();

    for (int it = 0; it < niter; it++) {
        int cur = it & 1;
        if (it + 1 < niter) {
            int k0 = (it + 1) * 64;
            #pragma unroll
            for (int hf = 0; hf < 2; hf++) {
                gl2lds16(agb + k0 + hf * 32, As + ((cur ^ 1) * 2 + hf) * 2048 + (w * 16) * 32);
                gl2lds16(bgb + k0 + hf * 32, Bs + ((cur ^ 1) * 2 + hf) * 2048 + (w * 16) * 32);
            }
        }
        #pragma unroll
        for (int ks = 0; ks < 2; ks++) {
            bfrag8 af[2], bf[2];
            #pragma unroll
            for (int mi = 0; mi < 2; mi++)
                af[mi] = *(const bfrag8*)&As[(cur * 2 + ks) * 2048 + (wm * 32 + mi * 16 + cl) * 32 + qg * 8];
            #pragma unroll
            for (int ni = 0; ni < 2; ni++)
                bf[ni] = *(const bfrag8*)&Bs[(cur * 2 + ks) * 2048 + (wn * 32 + ni * 16 + cl) * 32 + qg * 8];
            #pragma unroll
            for (int mi = 0; mi < 2; mi++)
                #pragma unroll
                for (int ni = 0; ni < 2; ni++)
                    acc[mi][ni] = __builtin_amdgcn_mfma_f32_16x16x32_bf16(af[mi], bf[ni], acc[mi][ni], 0, 0, 0);
        }
        if (it + 1 < niter) __syncthreads();
    }

    int bb = (EPI == 3) ? (colBase / 1536) : 0;   // batch idx (uniform per block)

    #pragma unroll
    for (int mi = 0; mi < 2; mi++) {
        #pragma unroll
        for (int ni = 0; ni < 2; ni++) {
            #pragma unroll
            for (int r = 0; r < 4; r++) {
                int row = rowBase + wm * 32 + mi * 16 + qg * 4 + r;
                int col = colBase + wn * 32 + ni * 16 + cl;
                float v = acc[mi][ni][r] + (EPI == 3 ? bias[row] : bias[col]);
                if (EPI == 0 && col < DIMC) v *= QSCALE_L2;
                if (EPI == 1) v = 0.5f * v * (1.0f + erff(v * 0.70710678118654752f));
                if (EPI == 2) {
                    v += resid[(size_t)row * Nn + col];
                    ((float*)out)[(size_t)row * Nn + col] = v;
                } else if (EPI == 3) {
                    // row = V output dim (0..511), col = global token
                    int t = col - bb * 1536;
                    int h = row >> 6, dl = row & 63;
                    int t32 = t & 31;
                    int slot = ((t32 & 15) >> 2) * 8 + (t32 >> 4) * 4 + (t32 & 3);
                    size_t a = ((size_t)(bb * 8 + h) * 48 + (t >> 5)) * 2048
                             + (dl >> 4) * 512 + (dl & 15) * 32 + slot;
                    _Float16 e = (_Float16)v;
                    ((ushort*)out)[a] = *(ushort*)&e;
                } else {
                    ((ushort*)out)[(size_t)row * Nn + col] = f2bf(v);
                }
            }
        }
    }
}

// ---------------- MFMA GEMM body (64x128): C = A @ Wt^T ---------------------
// 4 waves, each 32x64 out (acc 2x4). BK=64 single-barrier dbuf.
// EPI: 1 = +bias[col], GELU, store bf16 row-major
//      4 = +bias[col], store bf16 PACKED Q (out, cols<512, pre-scaled) /
//          K (out2, cols>=512) layouts
template <int EPI>
__device__ __forceinline__
void mgemm128_body(const ushort* __restrict__ A, const ushort* __restrict__ Wt,
                   const float* __restrict__ bias, void* out, void* out2,
                   int K, int Nn, int bx, int by,
                   ushort* As, ushort* Bs)   // As 16KB [2][2][64*32], Bs 32KB [2][2][128*32]
{
    int tid = threadIdx.x;
    int lane = tid & 63, w = tid >> 6;
    int cl = lane & 15, qg = lane >> 4;
    int wm = w >> 1, wn = w & 1;
    int rowBase = by * 64, colBase = bx * 128;
    int sr = lane >> 2;
    int sb = (lane & 3) * 8;

    const ushort* agb = A  + (size_t)(rowBase + w * 16 + sr) * K + sb;
    const ushort* bgb = Wt + (size_t)(colBase + w * 32 + sr) * K + sb;

    ffrag acc[2][4];
    #pragma unroll
    for (int mi = 0; mi < 2; mi++)
        #pragma unroll
        for (int ni = 0; ni < 4; ni++)
            #pragma unroll
            for (int r = 0; r < 4; r++) acc[mi][ni][r] = 0.f;

    int niter = K >> 6;

    #pragma unroll
    for (int hf = 0; hf < 2; hf++) {
        gl2lds16(agb + hf * 32,                  As + (0 * 2 + hf) * 2048 + (w * 16) * 32);
        gl2lds16(bgb + hf * 32,                  Bs + (0 * 2 + hf) * 4096 + (w * 32) * 32);
        gl2lds16(bgb + (size_t)16 * K + hf * 32, Bs + (0 * 2 + hf) * 4096 + (w * 32 + 16) * 32);
    }
    __syncthreads();

    for (int it = 0; it < niter; it++) {
        int cur = it & 1;
        if (it + 1 < niter) {
            int k0 = (it + 1) * 64;
            #pragma unroll
            for (int hf = 0; hf < 2; hf++) {
                gl2lds16(agb + k0 + hf * 32,                  As + ((cur ^ 1) * 2 + hf) * 2048 + (w * 16) * 32);
                gl2lds16(bgb + k0 + hf * 32,                  Bs + ((cur ^ 1) * 2 + hf) * 4096 + (w * 32) * 32);
                gl2lds16(bgb + (size_t)16 * K + k0 + hf * 32, Bs + ((cur ^ 1) * 2 + hf) * 4096 + (w * 32 + 16) * 32);
            }
        }
        #pragma unroll
        for (int ks = 0; ks < 2; ks++) {
            bfrag8 af[2], bf[4];
            #pragma unroll
            for (int mi = 0; mi < 2; mi++)
                af[mi] = *(const bfrag8*)&As[(cur * 2 + ks) * 2048 + (wm * 32 + mi * 16 + cl) * 32 + qg * 8];
            #pragma unroll
            for (int ni = 0; ni < 4; ni++)
                bf[ni] = *(const bfrag8*)&Bs[(cur * 2 + ks) * 4096 + (wn * 64 + ni * 16 + cl) * 32 + qg * 8];
            #pragma unroll
            for (int mi = 0; mi < 2; mi++)
                #pragma unroll
                for (int ni = 0; ni < 4; ni++)
                    acc[mi][ni] = __builtin_amdgcn_mfma_f32_16x16x32_bf16(af[mi], bf[ni], acc[mi][ni], 0, 0, 0);
        }
        if (it + 1 < niter) __syncthreads();
    }

    int bb = (EPI == 4) ? (rowBase / 1536) : 0;   // batch idx (uniform per block)

    #pragma unroll
    for (int mi = 0; mi < 2; mi++) {
        #pragma unroll
        for (int ni = 0; ni < 4; ni++) {
            #pragma unroll
            for (int r = 0; r < 4; r++) {
                int row = rowBase + wm * 32 + mi * 16 + qg * 4 + r;
                int col = colBase + wn * 64 + ni * 16 + cl;
                float v = acc[mi][ni][r] + bias[col];
                if (EPI == 1) {
                    v = 0.5f * v * (1.0f + erff(v * 0.70710678118654752f));
                    ((ushort*)out)[(size_t)row * Nn + col] = f2bf(v);
                } else if (EPI == 4) {
                    // row = global token, col = 0..1023 (q|k)
                    int t = row - bb * 1536;
                    int h = (col >> 6) & 7;
                    int d = col & 63;
                    size_t a = ((size_t)(bb * 8 + h) * 96 + (t >> 4)) * 1024
                             + (d >> 5) * 512 + (t & 15) * 32 + (d & 31);
                    if (col < DIMC) {
                        v *= QSCALE_L2;
                        ((ushort*)out)[a] = f2bf(v);
                    } else {
                        ((ushort*)out2)[a] = f2bf(v);
                    }
                }
            }
        }
    }
}

template <int EPI>
__global__ __launch_bounds__(256)
void mgemm_kernel(const ushort* __restrict__ A, const ushort* __restrict__ Wt,
                  const float* __restrict__ bias, const float* resid,
                  void* out, int M, int K, int Nn)
{
    __shared__ ushort As[2 * 2 * 64 * 32];
    __shared__ ushort Bs[2 * 2 * 64 * 32];
    mgemm_body<EPI>(A, Wt, bias, resid, out, M, K, Nn, blockIdx.x, blockIdx.y, As, Bs);
}

template <int EPI>
__global__ __launch_bounds__(256)
void mgemm128_kernel(const ushort* __restrict__ A, const ushort* __restrict__ Wt,
                     const float* __restrict__ bias, void* out, int K, int Nn)
{
    __shared__ ushort As[2 * 2 * 64 * 32];
    __shared__ ushort Bs[2 * 2 * 128 * 32];
    mgemm128_body<EPI>(A, Wt, bias, out, nullptr, K, Nn, blockIdx.x, blockIdx.y, As, Bs);
}

// fused: QK GEMM 64x128 tiles (blocks [0,768)) + V^T GEMM 64x64 (blocks [768,1536))
__global__ __launch_bounds__(256)
void qkvt_kernel(const ushort* __restrict__ h_bf, const ushort* __restrict__ qkv_wt,
                 const float* __restrict__ qkv_b, ushort* __restrict__ qpk,
                 ushort* __restrict__ kpk, ushort* __restrict__ vpk)
{
    __shared__ ushort smem[2 * 2 * 192 * 32];   // 48KB pool
    int bid = blockIdx.x;
    if (bid < 768) {
        // As = smem[0..16KB), Bs = smem[16KB..48KB)
        mgemm128_body<4>(h_bf, qkv_wt, qkv_b, (void*)qpk, (void*)kpk,
                         DIMC, 2 * DIMC, bid & 7, bid >> 3,
                         smem, smem + 2 * 2 * 64 * 32);
    } else {
        int b2 = bid - 768;
        mgemm_body<3>(qkv_wt + (size_t)2 * DIMC * DIMC, h_bf, qkv_b + 2 * DIMC, nullptr,
                      (void*)vpk, DIMC, DIMC, NROWS, b2 % 96, b2 / 96,
                      smem, smem + 2 * 2 * 64 * 32);
    }
}

// ---------------- barrier-free MFMA flash attention (packed-layout loads) ---
// VALU-cut version: softmax shift folded into QK C-init; denominator l
// computed on the MFMA pipe via a 0.25-constant A operand (each of the 4 qg
// copies then carries partial/4, so the existing 4-way qg reduction is exact).
__global__ __launch_bounds__(256)
void attn_kernel(const ushort* __restrict__ qpk, const ushort* __restrict__ kpk,
                 const ushort* __restrict__ vpk,
                 const float* __restrict__ x, float* __restrict__ xres)
{
    __shared__ float Op[48][68];          // merged O^T as [q-row][d] (13KB)
    __shared__ float Lp[4][4][16][3];     // partial l per (wave,qg,q16,seg) (3KB)

    int n = blockIdx.x + (blockIdx.y << 5);   // flat 0..1023
    int idx = n >> 3;
    int bh  = (n & 7) * 4 + (idx & 3);        // XCD-local bh grouping
    int qi0 = (idx >> 2) * 16;
    int b = bh >> 3, h = bh & 7;
    int tid = threadIdx.x;
    int lane = tid & 63, w = tid >> 6;
    int cl = lane & 15, qg = lane >> 4;

    // packed per-(b,h) bases; within each 1KB block lane offset = cl*32 + qg*8
    int lofs = cl * 32 + qg * 8;
    const ushort* qb = qpk + (size_t)bh * 96 * 1024;
    const ushort* kb = kpk + (size_t)bh * 96 * 1024;
    const ushort* vb = vpk + (size_t)bh * 48 * 2048;

    bfrag8 bq[3][2];
    #pragma unroll
    for (int seg = 0; seg < 3; seg++)
        #pragma unroll
        for (int f = 0; f < 2; f++)
            bq[seg][f] = *(const bfrag8*)&qb[(size_t)((seg * SSEG + qi0) >> 4) * 1024 + f * 512 + lofs];

    ffrag o[3][4];
    #pragma unroll
    for (int seg = 0; seg < 3; seg++)
        #pragma unroll
        for (int mg = 0; mg < 4; mg++)
            #pragma unroll
            for (int r = 0; r < 4; r++) o[seg][mg][r] = 0.f;
    ffrag ol[3];                 // MFMA-accumulated softmax denominators
    #pragma unroll
    for (int seg = 0; seg < 3; seg++)
        #pragma unroll
        for (int r = 0; r < 4; r++) ol[seg][r] = 0.f;

    hfrag8 vq;                   // 0.25-constant A operand for the l-MFMA
    #pragma unroll
    for (int j = 0; j < 8; j++) vq[j] = (_Float16)0.25f;

    int kb0 = w * 384;   // this wave's key range: 384 keys, 12 iters of 32

    const ushort* kptr = kb + (size_t)(kb0 >> 4) * 1024 + lofs;
    const ushort* vptr = vb + (size_t)(kb0 >> 5) * 2048 + lofs;

    auto loadf = [&](hfrag8* av, bfrag8 (*af)[2]) {
        #pragma unroll
        for (int mg = 0; mg < 4; mg++)
            av[mg] = *(const hfrag8*)(vptr + mg * 512);
        vptr += 2048;
        #pragma unroll
        for (int s = 0; s < 2; s++)
            #pragma unroll
            for (int f = 0; f < 2; f++)
                af[s][f] = *(const bfrag8*)(kptr + s * 1024 + f * 512);
        kptr += 2048;
    };

    auto comp = [&](const hfrag8* av, const bfrag8 (*af)[2]) {
        ffrag c[2][3];
        // shift folded into C-init: seg0 = -SHIFT, seg1/2 = -(1-ALPHA)*SHIFT
        #pragma unroll
        for (int s = 0; s < 2; s++)
            #pragma unroll
            for (int r = 0; r < 4; r++) {
                c[s][0][r] = -SHIFT_L2;
                c[s][1][r] = -HSHIFT_L2;
                c[s][2][r] = -HSHIFT_L2;
            }
        __builtin_amdgcn_s_setprio(1);
        #pragma unroll
        for (int s = 0; s < 2; s++)
            #pragma unroll
            for (int seg = 0; seg < 3; seg++) {
                c[s][seg] = __builtin_amdgcn_mfma_f32_16x16x32_bf16(af[s][0], bq[seg][0], c[s][seg], 0, 0, 0);
                c[s][seg] = __builtin_amdgcn_mfma_f32_16x16x32_bf16(af[s][1], bq[seg][1], c[s][seg], 0, 0, 0);
            }
        __builtin_amdgcn_s_setprio(0);
        #pragma unroll
        for (int s = 0; s < 2; s++) {
            #pragma unroll
            for (int r = 0; r < 4; r++) {
                float sh0 = c[s][0][r];                       // already shifted
                float sh1 = fmaf(ALPHA_C, sh0, c[s][1][r]);
                float sh2 = fmaf(ALPHA_C, sh1, c[s][2][r]);
                c[s][0][r] = __builtin_amdgcn_exp2f(sh0);
                c[s][1][r] = __builtin_amdgcn_exp2f(sh1);
                c[s][2][r] = __builtin_amdgcn_exp2f(sh2);
            }
        }
        #pragma unroll
        for (int seg = 0; seg < 3; seg++) {
            union { hfrag8 v8; h2 v2[4]; } u;
            u.v2[0] = __builtin_amdgcn_cvt_pkrtz(c[0][seg][0], c[0][seg][1]);
            u.v2[1] = __builtin_amdgcn_cvt_pkrtz(c[0][seg][2], c[0][seg][3]);
            u.v2[2] = __builtin_amdgcn_cvt_pkrtz(c[1][seg][0], c[1][seg][1]);
            u.v2[3] = __builtin_amdgcn_cvt_pkrtz(c[1][seg][2], c[1][seg][3]);
            __builtin_amdgcn_s_setprio(1);
            #pragma unroll
            for (int mg = 0; mg < 4; mg++)
                o[seg][mg] = __builtin_amdgcn_mfma_f32_16x16x32_f16(av[mg], u.v8, o[seg][mg], 0, 0, 0);
            // denominator on the MFMA pipe: 0.25-rows -> D[row][q] = 0.25*sum_k P[k][q]
            ol[seg] = __builtin_amdgcn_mfma_f32_16x16x32_f16(vq, u.v8, ol[seg], 0, 0, 0);
            __builtin_amdgcn_s_setprio(0);
        }
    };

    hfrag8 avA[4], avB[4];
    bfrag8 afA[2][2], afB[2][2];
    loadf(avA, afA);
    #pragma unroll 1
    for (int it = 0; it < 12; it += 2) {
        loadf(avB, afB);
        comp(avA, afA);
        if (it + 2 < 12) loadf(avA, afA);
        comp(avB, afB);
    }

    // ol[seg][0] = 0.25 * (full 32-key partial); 4 qg copies sum to the exact partial
    #pragma unroll
    for (int seg = 0; seg < 3; seg++) Lp[w][qg][cl][seg] = ol[seg][0];

    #pragma unroll 1
    for (int wv = 0; wv < 4; wv++) {
        __syncthreads();
        if (w == wv) {
            #pragma unroll
            for (int seg = 0; seg < 3; seg++)
                #pragma unroll
                for (int mg = 0; mg < 4; mg++) {
                    float* dst = &Op[seg * 16 + cl][mg * 16 + qg * 4];
                    if (wv == 0) {
                        #pragma unroll
                        for (int r = 0; r < 4; r++) dst[r] = o[seg][mg][r];
                    } else {
                        #pragma unroll
                        for (int r = 0; r < 4; r++) dst[r] += o[seg][mg][r];
                    }
                }
        }
    }
    __syncthreads();

    if (tid < 192) {
        int row = tid >> 2;
        int seg = row >> 4, q16 = row & 15;
        int d0 = (tid & 3) * 16;
        float l = 0.f;
        #pragma unroll
        for (int wv = 0; wv < 4; wv++)
            #pragma unroll
            for (int g2 = 0; g2 < 4; g2++)
                l += Lp[wv][g2][q16][seg];
        float invl = 1.0f / l;
        size_t rowg = ((size_t)(b * NSEQ + seg * SSEG + qi0 + q16)) * DIMC + h * HDIM + d0;
        #pragma unroll
        for (int dd = 0; dd < 16; dd += 4) {
            f4 xv = *(const f4*)(x + rowg + dd);
            f4 ov;
            ov.x = Op[row][d0 + dd + 0] * invl + xv.x;
            ov.y = Op[row][d0 + dd + 1] * invl + xv.y;
            ov.z = Op[row][d0 + dd + 2] * invl + xv.z;
            ov.w = Op[row][d0 + dd + 3] * invl + xv.w;
            *(f4*)(xres + rowg + dd) = ov;
        }
    }
}

// ---------------- launch --------------------------------------------------
extern "C" void kernel_launch(void* const* d_in, const int* in_sizes, int n_in,
                              void* d_out, int out_size, void* d_ws, size_t ws_size,
                              hipStream_t stream)
{
    const float* x     = (const float*)d_in[0];
    const float* ln1_g = (const float*)d_in[1];
    const float* ln1_b = (const float*)d_in[2];
    const float* qkv_w = (const float*)d_in[3];
    const float* qkv_b = (const float*)d_in[4];
    const float* ln2_g = (const float*)d_in[5];
    const float* ln2_b = (const float*)d_in[6];
    const float* fc1_w = (const float*)d_in[7];
    const float* fc1_b = (const float*)d_in[8];
    const float* fc2_w = (const float*)d_in[9];
    const float* fc2_b = (const float*)d_in[10];
    float* out = (float*)d_out;

    // workspace layout (bf16/f16 as ushort)
    char* p = (char*)d_ws;
    ushort* h_bf    = (ushort*)p;  p += (size_t)NROWS * DIMC * 2;        // 6.3 MB
    ushort* qpk     = (ushort*)p;  p += (size_t)32 * 96 * 1024 * 2;      // 6.3 MB packed Q
    ushort* kpk     = (ushort*)p;  p += (size_t)32 * 96 * 1024 * 2;      // 6.3 MB packed K
    ushort* vpk     = (ushort*)p;  p += (size_t)32 * 48 * 2048 * 2;      // 6.3 MB packed V (f16)
    ushort* mid     = (ushort*)p;  p += (size_t)NROWS * HIDDEN_DIM * 2;  // 12.6 MB
    ushort* qkv_wt  = (ushort*)p;  p += (size_t)3 * DIMC * DIMC * 2;     // 1.57 MB
    ushort* fc1_wt  = (ushort*)p;  p += (size_t)HIDDEN_DIM * DIMC * 2;   // 1.05 MB
    ushort* fc2_wt  = (ushort*)p;                                        // 1.05 MB
    float* xres = out;

    // 0. fused weight transpose-converts + LN1 (448 + 6144 blocks)
    prep_kernel<<<448 + NROWS, 256, 0, stream>>>(qkv_w, fc1_w, fc2_w, qkv_wt, fc1_wt, fc2_wt,
                                                 x, ln1_g, ln1_b, h_bf);

    // 2. fused Q/K GEMM (64x128 tiles, packed store) + V^T GEMM (64x64, packed)
    qkvt_kernel<<<1536, 256, 0, stream>>>(h_bf, qkv_wt, qkv_b, qpk, kpk, vpk);

    // 3. pipelined barrier-free MFMA flash attention + residual -> xres (d_out)
    attn_kernel<<<dim3(SSEG / 16, BATCH * NHEADS), 256, 0, stream>>>(qpk, kpk, vpk, x, xres);

    // 4. LN2 -> bf16 h
    ln_kernel<<<NROWS, 256, 0, stream>>>(xres, ln2_g, ln2_b, h_bf);

    // 5. FC1 + GELU -> bf16 mid (64x128 tiles, 8x96 = 768 blocks)
    mgemm128_kernel<1><<<dim3(HIDDEN_DIM / 128, NROWS / 64), 256, 0, stream>>>(
        h_bf, fc1_wt, fc1_b, (void*)mid, DIMC, HIDDEN_DIM);

    // 6. FC2 + residual -> f32 out (64x64)
    mgemm_kernel<2><<<dim3(DIMC / 64, NROWS / 64), 256, 0, stream>>>(
        mid, fc2_wt, fc2_b, xres, (void*)out, NROWS, HIDDEN_DIM, DIMC);
}

// Round 4
// 190.885 us; speedup vs baseline: 1.0925x; 1.0925x over previous
//
#include <hip/hip_runtime.h>
#include <hip/hip_bf16.h>
#include <math.h>

#define DIMC 512
#define NSEQ 1536
#define BATCH 4
#define NHEADS 8
#define HDIM 64
#define SSEG 512          // NSEQ/3
#define HIDDEN_DIM 1024
#define ALPHA_C 0.5f
#define EPS_C 1e-5f
#define NROWS (BATCH*NSEQ) // 6144
#define SHIFT_L2 8.65617025f    // 6.0 * log2(e): static softmax shift, base-2 units
#define HSHIFT_L2 4.328085125f  // (1-ALPHA)*SHIFT_L2, for seg1/seg2 C-init folding
#define QSCALE_L2 0.18033688f   // 0.125 * log2(e): folded into Q at GEMM epilogue

typedef __attribute__((ext_vector_type(8))) short bfrag8;      // 8 bf16
typedef __attribute__((ext_vector_type(8))) _Float16 hfrag8;   // 8 f16
typedef __attribute__((ext_vector_type(2))) __fp16 h2;         // cvt_pkrtz result type
typedef __attribute__((ext_vector_type(4))) float ffrag;       // 4 f32 acc
typedef float4 f4;

// Packed per-(b,h) fragment-contiguous layouts so attention loads are 1KB bursts:
//  Qp/Kp: [bh][96 key16blk][f<2][cl<16][qg<4][j<8]  bf16  (1024 elems / 16-token blk)
//  Vp:    [bh][48 key32blk][mg<4][cl<16][qg<4][j<8] f16   (2048 elems / 32-token blk)

__device__ __forceinline__ ushort f2bf(float v) {
    __hip_bfloat16 hb = __float2bfloat16(v);
    return *(ushort*)&hb;
}

// async global->LDS, 16B per lane; lds dest = wave-uniform base + lane*16
__device__ __forceinline__ void gl2lds16(const ushort* g, ushort* l) {
    __builtin_amdgcn_global_load_lds(
        (const __attribute__((address_space(1))) unsigned*)g,
        (__attribute__((address_space(3))) unsigned*)l, 16, 0, 0);
}

// ---------------- fused prep: weight transpose-converts + LN1 ---------------
__global__ __launch_bounds__(256)
void prep_kernel(const float* __restrict__ qkv_w, const float* __restrict__ fc1_w,
                 const float* __restrict__ fc2_w, ushort* __restrict__ qkv_wt,
                 ushort* __restrict__ fc1_wt, ushort* __restrict__ fc2_wt,
                 const float* __restrict__ x, const float* __restrict__ g,
                 const float* __restrict__ bvec, ushort* __restrict__ h_out)
{
    int bid = blockIdx.x;
    if (bid < 448) {
        __shared__ float tile[64][65];
        const float* W; ushort* Wt; int K, N, n0, k0;
        if (bid < 192)      { W = qkv_w; Wt = qkv_wt; K = 512;  N = 1536; int b = bid;       n0 = (b % 24) * 64; k0 = (b / 24) * 64; }
        else if (bid < 320) { W = fc1_w; Wt = fc1_wt; K = 512;  N = 1024; int b = bid - 192; n0 = (b % 16) * 64; k0 = (b / 16) * 64; }
        else                { W = fc2_w; Wt = fc2_wt; K = 1024; N = 512;  int b = bid - 320; n0 = (b % 8)  * 64; k0 = (b / 8)  * 64; }
        int tx = threadIdx.x & 63, ty = threadIdx.x >> 6;
        #pragma unroll
        for (int i = 0; i < 16; i++) {
            int r = i * 4 + ty;
            tile[r][tx] = W[(size_t)(k0 + r) * N + n0 + tx];
        }
        __syncthreads();
        #pragma unroll
        for (int i = 0; i < 16; i++) {
            int r = i * 4 + ty;
            Wt[(size_t)(n0 + r) * K + k0 + tx] = f2bf(tile[tx][r]);
        }
    } else {
        __shared__ float red[16];
        int row = bid - 448;
        int t = threadIdx.x;
        int lane = t & 63, w = t >> 6;
        const float* rp = x + (size_t)row * DIMC;
        float v0 = rp[t];
        float v1 = rp[t + 256];
        float s = v0 + v1;
        float s2 = v0 * v0 + v1 * v1;
        #pragma unroll
        for (int o = 32; o > 0; o >>= 1) {
            s  += __shfl_down(s,  o, 64);
            s2 += __shfl_down(s2, o, 64);
        }
        if (lane == 0) { red[w] = s; red[8 + w] = s2; }
        __syncthreads();
        if (t == 0) {
            float a = red[0] + red[1] + red[2] + red[3];
            float c = red[8] + red[9] + red[10] + red[11];
            red[0] = a; red[8] = c;
        }
        __syncthreads();
        float mean = red[0] * (1.0f / DIMC);
        float var  = red[8] * (1.0f / DIMC) - mean * mean;
        float rstd = rsqrtf(var + EPS_C);
        ushort* op = h_out + (size_t)row * DIMC;
        op[t]       = f2bf((v0 - mean) * rstd * g[t]       + bvec[t]);
        op[t + 256] = f2bf((v1 - mean) * rstd * g[t + 256] + bvec[t + 256]);
    }
}

// ---------------- LayerNorm: fp32 in -> bf16 out ----------------------------
__global__ __launch_bounds__(256)
void ln_kernel(const float* __restrict__ in, const float* __restrict__ g,
               const float* __restrict__ b, ushort* __restrict__ out)
{
    __shared__ float red[16];
    int row = blockIdx.x;
    int t = threadIdx.x;
    int lane = t & 63, w = t >> 6;
    const float* rp = in + (size_t)row * DIMC;
    float v0 = rp[t];
    float v1 = rp[t + 256];
    float s = v0 + v1;
    float s2 = v0 * v0 + v1 * v1;
    #pragma unroll
    for (int o = 32; o > 0; o >>= 1) {
        s  += __shfl_down(s,  o, 64);
        s2 += __shfl_down(s2, o, 64);
    }
    if (lane == 0) { red[w] = s; red[8 + w] = s2; }
    __syncthreads();
    if (t == 0) {
        float a = red[0] + red[1] + red[2] + red[3];
        float c = red[8] + red[9] + red[10] + red[11];
        red[0] = a; red[8] = c;
    }
    __syncthreads();
    float mean = red[0] * (1.0f / DIMC);
    float var  = red[8] * (1.0f / DIMC) - mean * mean;
    float rstd = rsqrtf(var + EPS_C);
    ushort* op = out + (size_t)row * DIMC;
    op[t]       = f2bf((v0 - mean) * rstd * g[t]       + b[t]);
    op[t + 256] = f2bf((v1 - mean) * rstd * g[t + 256] + b[t + 256]);
}

// ---------------- MFMA GEMM body (64x64): C = A @ Wt^T ----------------------
// EPI: 0 = +bias[col], store bf16 (QK: cols<512 pre-scaled)
//      1 = +bias[col], exact GELU, store bf16
//      2 = +bias[col] +resid(f32), store f32
//      3 = +bias[row], store f16 PACKED V layout (see header comment)
template <int EPI>
__device__ __forceinline__
void mgemm_body(const ushort* __restrict__ A, const ushort* __restrict__ Wt,
                const float* __restrict__ bias, const float* resid,
                void* out, int M, int K, int Nn, int bx, int by,
                ushort* As, ushort* Bs)   // each [2][2][64*32] = 16KB
{
    int tid = threadIdx.x;
    int lane = tid & 63, w = tid >> 6;
    int cl = lane & 15, qg = lane >> 4;
    int wm = w >> 1, wn = w & 1;
    int rowBase = by * 64, colBase = bx * 64;
    int sr = lane >> 2;
    int sb = (lane & 3) * 8;

    const ushort* agb = A  + (size_t)(rowBase + w * 16 + sr) * K + sb;
    const ushort* bgb = Wt + (size_t)(colBase + w * 16 + sr) * K + sb;

    ffrag acc[2][2];
    #pragma unroll
    for (int mi = 0; mi < 2; mi++)
        #pragma unroll
        for (int ni = 0; ni < 2; ni++)
            #pragma unroll
            for (int r = 0; r < 4; r++) acc[mi][ni][r] = 0.f;

    int niter = K >> 6;

    #pragma unroll
    for (int hf = 0; hf < 2; hf++) {
        gl2lds16(agb + hf * 32, As + (0 * 2 + hf) * 2048 + (w * 16) * 32);
        gl2lds16(bgb + hf * 32, Bs + (0 * 2 + hf) * 2048 + (w * 16) * 32);
    }
    __syncthreads();

    for (int it = 0; it < niter; it++) {
        int cur = it & 1;
        if (it + 1 < niter) {
            int k0 = (it + 1) * 64;
            #pragma unroll
            for (int hf = 0; hf < 2; hf++) {
                gl2lds16(agb + k0 + hf * 32, As + ((cur ^ 1) * 2 + hf) * 2048 + (w * 16) * 32);
                gl2lds16(bgb + k0 + hf * 32, Bs + ((cur ^ 1) * 2 + hf) * 2048 + (w * 16) * 32);
            }
        }
        #pragma unroll
        for (int ks = 0; ks < 2; ks++) {
            bfrag8 af[2], bf[2];
            #pragma unroll
            for (int mi = 0; mi < 2; mi++)
                af[mi] = *(const bfrag8*)&As[(cur * 2 + ks) * 2048 + (wm * 32 + mi * 16 + cl) * 32 + qg * 8];
            #pragma unroll
            for (int ni = 0; ni < 2; ni++)
                bf[ni] = *(const bfrag8*)&Bs[(cur * 2 + ks) * 2048 + (wn * 32 + ni * 16 + cl) * 32 + qg * 8];
            #pragma unroll
            for (int mi = 0; mi < 2; mi++)
                #pragma unroll
                for (int ni = 0; ni < 2; ni++)
                    acc[mi][ni] = __builtin_amdgcn_mfma_f32_16x16x32_bf16(af[mi], bf[ni], acc[mi][ni], 0, 0, 0);
        }
        if (it + 1 < niter) __syncthreads();
    }

    int bb = (EPI == 3) ? (colBase / 1536) : 0;   // batch idx (uniform per block)

    #pragma unroll
    for (int mi = 0; mi < 2; mi++) {
        #pragma unroll
        for (int ni = 0; ni < 2; ni++) {
            #pragma unroll
            for (int r = 0; r < 4; r++) {
                int row = rowBase + wm * 32 + mi * 16 + qg * 4 + r;
                int col = colBase + wn * 32 + ni * 16 + cl;
                float v = acc[mi][ni][r] + (EPI == 3 ? bias[row] : bias[col]);
                if (EPI == 0 && col < DIMC) v *= QSCALE_L2;
                if (EPI == 1) v = 0.5f * v * (1.0f + erff(v * 0.70710678118654752f));
                if (EPI == 2) {
                    v += resid[(size_t)row * Nn + col];
                    ((float*)out)[(size_t)row * Nn + col] = v;
                } else if (EPI == 3) {
                    // row = V output dim (0..511), col = global token
                    int t = col - bb * 1536;
                    int h = row >> 6, dl = row & 63;
                    int t32 = t & 31;
                    int slot = ((t32 & 15) >> 2) * 8 + (t32 >> 4) * 4 + (t32 & 3);
                    size_t a = ((size_t)(bb * 8 + h) * 48 + (t >> 5)) * 2048
                             + (dl >> 4) * 512 + (dl & 15) * 32 + slot;
                    _Float16 e = (_Float16)v;
                    ((ushort*)out)[a] = *(ushort*)&e;
                } else {
                    ((ushort*)out)[(size_t)row * Nn + col] = f2bf(v);
                }
            }
        }
    }
}

// ---------------- MFMA GEMM body (64x128): C = A @ Wt^T ---------------------
// 4 waves, each 32x64 out (acc 2x4). BK=64 single-barrier dbuf.
// EPI: 1 = +bias[col], GELU, store bf16 row-major
//      4 = +bias[col], store bf16 PACKED Q (out, cols<512, pre-scaled) /
//          K (out2, cols>=512) layouts
template <int EPI>
__device__ __forceinline__
void mgemm128_body(const ushort* __restrict__ A, const ushort* __restrict__ Wt,
                   const float* __restrict__ bias, void* out, void* out2,
                   int K, int Nn, int bx, int by,
                   ushort* As, ushort* Bs)   // As 16KB [2][2][64*32], Bs 32KB [2][2][128*32]
{
    int tid = threadIdx.x;
    int lane = tid & 63, w = tid >> 6;
    int cl = lane & 15, qg = lane >> 4;
    int wm = w >> 1, wn = w & 1;
    int rowBase = by * 64, colBase = bx * 128;
    int sr = lane >> 2;
    int sb = (lane & 3) * 8;

    const ushort* agb = A  + (size_t)(rowBase + w * 16 + sr) * K + sb;
    const ushort* bgb = Wt + (size_t)(colBase + w * 32 + sr) * K + sb;

    ffrag acc[2][4];
    #pragma unroll
    for (int mi = 0; mi < 2; mi++)
        #pragma unroll
        for (int ni = 0; ni < 4; ni++)
            #pragma unroll
            for (int r = 0; r < 4; r++) acc[mi][ni][r] = 0.f;

    int niter = K >> 6;

    #pragma unroll
    for (int hf = 0; hf < 2; hf++) {
        gl2lds16(agb + hf * 32,                  As + (0 * 2 + hf) * 2048 + (w * 16) * 32);
        gl2lds16(bgb + hf * 32,                  Bs + (0 * 2 + hf) * 4096 + (w * 32) * 32);
        gl2lds16(bgb + (size_t)16 * K + hf * 32, Bs + (0 * 2 + hf) * 4096 + (w * 32 + 16) * 32);
    }
    __syncthreads();

    for (int it = 0; it < niter; it++) {
        int cur = it & 1;
        if (it + 1 < niter) {
            int k0 = (it + 1) * 64;
            #pragma unroll
            for (int hf = 0; hf < 2; hf++) {
                gl2lds16(agb + k0 + hf * 32,                  As + ((cur ^ 1) * 2 + hf) * 2048 + (w * 16) * 32);
                gl2lds16(bgb + k0 + hf * 32,                  Bs + ((cur ^ 1) * 2 + hf) * 4096 + (w * 32) * 32);
                gl2lds16(bgb + (size_t)16 * K + k0 + hf * 32, Bs + ((cur ^ 1) * 2 + hf) * 4096 + (w * 32 + 16) * 32);
            }
        }
        #pragma unroll
        for (int ks = 0; ks < 2; ks++) {
            bfrag8 af[2], bf[4];
            #pragma unroll
            for (int mi = 0; mi < 2; mi++)
                af[mi] = *(const bfrag8*)&As[(cur * 2 + ks) * 2048 + (wm * 32 + mi * 16 + cl) * 32 + qg * 8];
            #pragma unroll
            for (int ni = 0; ni < 4; ni++)
                bf[ni] = *(const bfrag8*)&Bs[(cur * 2 + ks) * 4096 + (wn * 64 + ni * 16 + cl) * 32 + qg * 8];
            #pragma unroll
            for (int mi = 0; mi < 2; mi++)
                #pragma unroll
                for (int ni = 0; ni < 4; ni++)
                    acc[mi][ni] = __builtin_amdgcn_mfma_f32_16x16x32_bf16(af[mi], bf[ni], acc[mi][ni], 0, 0, 0);
        }
        if (it + 1 < niter) __syncthreads();
    }

    int bb = (EPI == 4) ? (rowBase / 1536) : 0;   // batch idx (uniform per block)

    #pragma unroll
    for (int mi = 0; mi < 2; mi++) {
        #pragma unroll
        for (int ni = 0; ni < 4; ni++) {
            #pragma unroll
            for (int r = 0; r < 4; r++) {
                int row = rowBase + wm * 32 + mi * 16 + qg * 4 + r;
                int col = colBase + wn * 64 + ni * 16 + cl;
                float v = acc[mi][ni][r] + bias[col];
                if (EPI == 1) {
                    v = 0.5f * v * (1.0f + erff(v * 0.70710678118654752f));
                    ((ushort*)out)[(size_t)row * Nn + col] = f2bf(v);
                } else if (EPI == 4) {
                    // row = global token, col = 0..1023 (q|k)
                    int t = row - bb * 1536;
                    int h = (col >> 6) & 7;
                    int d = col & 63;
                    size_t a = ((size_t)(bb * 8 + h) * 96 + (t >> 4)) * 1024
                             + (d >> 5) * 512 + (t & 15) * 32 + (d & 31);
                    if (col < DIMC) {
                        v *= QSCALE_L2;
                        ((ushort*)out)[a] = f2bf(v);
                    } else {
                        ((ushort*)out2)[a] = f2bf(v);
                    }
                }
            }
        }
    }
}

template <int EPI>
__global__ __launch_bounds__(256)
void mgemm_kernel(const ushort* __restrict__ A, const ushort* __restrict__ Wt,
                  const float* __restrict__ bias, const float* resid,
                  void* out, int M, int K, int Nn)
{
    __shared__ ushort As[2 * 2 * 64 * 32];
    __shared__ ushort Bs[2 * 2 * 64 * 32];
    mgemm_body<EPI>(A, Wt, bias, resid, out, M, K, Nn, blockIdx.x, blockIdx.y, As, Bs);
}

template <int EPI>
__global__ __launch_bounds__(256)
void mgemm128_kernel(const ushort* __restrict__ A, const ushort* __restrict__ Wt,
                     const float* __restrict__ bias, void* out, int K, int Nn)
{
    __shared__ ushort As[2 * 2 * 64 * 32];
    __shared__ ushort Bs[2 * 2 * 128 * 32];
    mgemm128_body<EPI>(A, Wt, bias, out, nullptr, K, Nn, blockIdx.x, blockIdx.y, As, Bs);
}

// fused: QK GEMM 64x128 tiles (blocks [0,768)) + V^T GEMM 64x64 (blocks [768,1536))
__global__ __launch_bounds__(256)
void qkvt_kernel(const ushort* __restrict__ h_bf, const ushort* __restrict__ qkv_wt,
                 const float* __restrict__ qkv_b, ushort* __restrict__ qpk,
                 ushort* __restrict__ kpk, ushort* __restrict__ vpk)
{
    __shared__ ushort smem[2 * 2 * 192 * 32];   // 48KB pool
    int bid = blockIdx.x;
    if (bid < 768) {
        // As = smem[0..16KB), Bs = smem[16KB..48KB)
        mgemm128_body<4>(h_bf, qkv_wt, qkv_b, (void*)qpk, (void*)kpk,
                         DIMC, 2 * DIMC, bid & 7, bid >> 3,
                         smem, smem + 2 * 2 * 64 * 32);
    } else {
        int b2 = bid - 768;
        mgemm_body<3>(qkv_wt + (size_t)2 * DIMC * DIMC, h_bf, qkv_b + 2 * DIMC, nullptr,
                      (void*)vpk, DIMC, DIMC, NROWS, b2 % 96, b2 / 96,
                      smem, smem + 2 * 2 * 64 * 32);
    }
}

// ---------------- barrier-free MFMA flash attention (packed-layout loads) ---
// Register-neutral VALU cuts only: softmax shift folded into QK C-init
// (inline-constant v_mov, no extra VGPRs) and denominator accumulated with
// v_dot2_f32_f16 on the packed P pairs (12 fdot2 replace 24 f32 adds).
__global__ __launch_bounds__(256)
void attn_kernel(const ushort* __restrict__ qpk, const ushort* __restrict__ kpk,
                 const ushort* __restrict__ vpk,
                 const float* __restrict__ x, float* __restrict__ xres)
{
    __shared__ float Op[48][68];          // merged O^T as [q-row][d] (13KB)
    __shared__ float Lp[4][4][16][3];     // partial l per (wave,qg,q16,seg) (3KB)

    int n = blockIdx.x + (blockIdx.y << 5);   // flat 0..1023
    int idx = n >> 3;
    int bh  = (n & 7) * 4 + (idx & 3);        // XCD-local bh grouping
    int qi0 = (idx >> 2) * 16;
    int b = bh >> 3, h = bh & 7;
    int tid = threadIdx.x;
    int lane = tid & 63, w = tid >> 6;
    int cl = lane & 15, qg = lane >> 4;

    // packed per-(b,h) bases; within each 1KB block lane offset = cl*32 + qg*8
    int lofs = cl * 32 + qg * 8;
    const ushort* qb = qpk + (size_t)bh * 96 * 1024;
    const ushort* kb = kpk + (size_t)bh * 96 * 1024;
    const ushort* vb = vpk + (size_t)bh * 48 * 2048;

    bfrag8 bq[3][2];
    #pragma unroll
    for (int seg = 0; seg < 3; seg++)
        #pragma unroll
        for (int f = 0; f < 2; f++)
            bq[seg][f] = *(const bfrag8*)&qb[(size_t)((seg * SSEG + qi0) >> 4) * 1024 + f * 512 + lofs];

    ffrag o[3][4];
    #pragma unroll
    for (int seg = 0; seg < 3; seg++)
        #pragma unroll
        for (int mg = 0; mg < 4; mg++)
            #pragma unroll
            for (int r = 0; r < 4; r++) o[seg][mg][r] = 0.f;
    float lp[3] = {0.f, 0.f, 0.f};

    h2 one2;
    one2[0] = (__fp16)1.0f; one2[1] = (__fp16)1.0f;

    int kb0 = w * 384;   // this wave's key range: 384 keys, 12 iters of 32

    const ushort* kptr = kb + (size_t)(kb0 >> 4) * 1024 + lofs;
    const ushort* vptr = vb + (size_t)(kb0 >> 5) * 2048 + lofs;

    auto loadf = [&](hfrag8* av, bfrag8 (*af)[2]) {
        #pragma unroll
        for (int mg = 0; mg < 4; mg++)
            av[mg] = *(const hfrag8*)(vptr + mg * 512);
        vptr += 2048;
        #pragma unroll
        for (int s = 0; s < 2; s++)
            #pragma unroll
            for (int f = 0; f < 2; f++)
                af[s][f] = *(const bfrag8*)(kptr + s * 1024 + f * 512);
        kptr += 2048;
    };

    auto comp = [&](const hfrag8* av, const bfrag8 (*af)[2]) {
        ffrag c[2][3];
        // shift folded into C-init: seg0 = -SHIFT, seg1/2 = -(1-ALPHA)*SHIFT
        #pragma unroll
        for (int s = 0; s < 2; s++) {
            #pragma unroll
            for (int r = 0; r < 4; r++) {
                c[s][0][r] = -SHIFT_L2;
                c[s][1][r] = -HSHIFT_L2;
                c[s][2][r] = -HSHIFT_L2;
            }
            #pragma unroll
            for (int seg = 0; seg < 3; seg++) {
                c[s][seg] = __builtin_amdgcn_mfma_f32_16x16x32_bf16(af[s][0], bq[seg][0], c[s][seg], 0, 0, 0);
                c[s][seg] = __builtin_amdgcn_mfma_f32_16x16x32_bf16(af[s][1], bq[seg][1], c[s][seg], 0, 0, 0);
            }
        }
        #pragma unroll
        for (int s = 0; s < 2; s++) {
            #pragma unroll
            for (int r = 0; r < 4; r++) {
                float sh0 = c[s][0][r];                       // already shifted
                float sh1 = fmaf(ALPHA_C, sh0, c[s][1][r]);
                float sh2 = fmaf(ALPHA_C, sh1, c[s][2][r]);
                c[s][0][r] = __builtin_amdgcn_exp2f(sh0);
                c[s][1][r] = __builtin_amdgcn_exp2f(sh1);
                c[s][2][r] = __builtin_amdgcn_exp2f(sh2);
            }
        }
        #pragma unroll
        for (int seg = 0; seg < 3; seg++) {
            union { hfrag8 v8; h2 v2[4]; } u;
            u.v2[0] = __builtin_amdgcn_cvt_pkrtz(c[0][seg][0], c[0][seg][1]);
            u.v2[1] = __builtin_amdgcn_cvt_pkrtz(c[0][seg][2], c[0][seg][3]);
            u.v2[2] = __builtin_amdgcn_cvt_pkrtz(c[1][seg][0], c[1][seg][1]);
            u.v2[3] = __builtin_amdgcn_cvt_pkrtz(c[1][seg][2], c[1][seg][3]);
            // denominator on packed pairs: 4 fdot2 per seg (replaces 8 f32 adds)
            lp[seg] = __builtin_amdgcn_fdot2(u.v2[0], one2, lp[seg], false);
            lp[seg] = __builtin_amdgcn_fdot2(u.v2[1], one2, lp[seg], false);
            lp[seg] = __builtin_amdgcn_fdot2(u.v2[2], one2, lp[seg], false);
            lp[seg] = __builtin_amdgcn_fdot2(u.v2[3], one2, lp[seg], false);
            #pragma unroll
            for (int mg = 0; mg < 4; mg++)
                o[seg][mg] = __builtin_amdgcn_mfma_f32_16x16x32_f16(av[mg], u.v8, o[seg][mg], 0, 0, 0);
        }
    };

    hfrag8 avA[4], avB[4];
    bfrag8 afA[2][2], afB[2][2];
    loadf(avA, afA);
    #pragma unroll 1
    for (int it = 0; it < 12; it += 2) {
        loadf(avB, afB);
        comp(avA, afA);
        if (it + 2 < 12) loadf(avA, afA);
        comp(avB, afB);
    }

    #pragma unroll
    for (int seg = 0; seg < 3; seg++) Lp[w][qg][cl][seg] = lp[seg];

    #pragma unroll 1
    for (int wv = 0; wv < 4; wv++) {
        __syncthreads();
        if (w == wv) {
            #pragma unroll
            for (int seg = 0; seg < 3; seg++)
                #pragma unroll
                for (int mg = 0; mg < 4; mg++) {
                    float* dst = &Op[seg * 16 + cl][mg * 16 + qg * 4];
                    if (wv == 0) {
                        #pragma unroll
                        for (int r = 0; r < 4; r++) dst[r] = o[seg][mg][r];
                    } else {
                        #pragma unroll
                        for (int r = 0; r < 4; r++) dst[r] += o[seg][mg][r];
                    }
                }
        }
    }
    __syncthreads();

    if (tid < 192) {
        int row = tid >> 2;
        int seg = row >> 4, q16 = row & 15;
        int d0 = (tid & 3) * 16;
        float l = 0.f;
        #pragma unroll
        for (int wv = 0; wv < 4; wv++)
            #pragma unroll
            for (int g2 = 0; g2 < 4; g2++)
                l += Lp[wv][g2][q16][seg];
        float invl = 1.0f / l;
        size_t rowg = ((size_t)(b * NSEQ + seg * SSEG + qi0 + q16)) * DIMC + h * HDIM + d0;
        #pragma unroll
        for (int dd = 0; dd < 16; dd += 4) {
            f4 xv = *(const f4*)(x + rowg + dd);
            f4 ov;
            ov.x = Op[row][d0 + dd + 0] * invl + xv.x;
            ov.y = Op[row][d0 + dd + 1] * invl + xv.y;
            ov.z = Op[row][d0 + dd + 2] * invl + xv.z;
            ov.w = Op[row][d0 + dd + 3] * invl + xv.w;
            *(f4*)(xres + rowg + dd) = ov;
        }
    }
}

// ---------------- launch --------------------------------------------------
extern "C" void kernel_launch(void* const* d_in, const int* in_sizes, int n_in,
                              void* d_out, int out_size, void* d_ws, size_t ws_size,
                              hipStream_t stream)
{
    const float* x     = (const float*)d_in[0];
    const float* ln1_g = (const float*)d_in[1];
    const float* ln1_b = (const float*)d_in[2];
    const float* qkv_w = (const float*)d_in[3];
    const float* qkv_b = (const float*)d_in[4];
    const float* ln2_g = (const float*)d_in[5];
    const float* ln2_b = (const float*)d_in[6];
    const float* fc1_w = (const float*)d_in[7];
    const float* fc1_b = (const float*)d_in[8];
    const float* fc2_w = (const float*)d_in[9];
    const float* fc2_b = (const float*)d_in[10];
    float* out = (float*)d_out;

    // workspace layout (bf16/f16 as ushort)
    char* p = (char*)d_ws;
    ushort* h_bf    = (ushort*)p;  p += (size_t)NROWS * DIMC * 2;        // 6.3 MB
    ushort* qpk     = (ushort*)p;  p += (size_t)32 * 96 * 1024 * 2;      // 6.3 MB packed Q
    ushort* kpk     = (ushort*)p;  p += (size_t)32 * 96 * 1024 * 2;      // 6.3 MB packed K
    ushort* vpk     = (ushort*)p;  p += (size_t)32 * 48 * 2048 * 2;      // 6.3 MB packed V (f16)
    ushort* mid     = (ushort*)p;  p += (size_t)NROWS * HIDDEN_DIM * 2;  // 12.6 MB
    ushort* qkv_wt  = (ushort*)p;  p += (size_t)3 * DIMC * DIMC * 2;     // 1.57 MB
    ushort* fc1_wt  = (ushort*)p;  p += (size_t)HIDDEN_DIM * DIMC * 2;   // 1.05 MB
    ushort* fc2_wt  = (ushort*)p;                                        // 1.05 MB
    float* xres = out;

    // 0. fused weight transpose-converts + LN1 (448 + 6144 blocks)
    prep_kernel<<<448 + NROWS, 256, 0, stream>>>(qkv_w, fc1_w, fc2_w, qkv_wt, fc1_wt, fc2_wt,
                                                 x, ln1_g, ln1_b, h_bf);

    // 2. fused Q/K GEMM (64x128 tiles, packed store) + V^T GEMM (64x64, packed)
    qkvt_kernel<<<1536, 256, 0, stream>>>(h_bf, qkv_wt, qkv_b, qpk, kpk, vpk);

    // 3. pipelined barrier-free MFMA flash attention + residual -> xres (d_out)
    attn_kernel<<<dim3(SSEG / 16, BATCH * NHEADS), 256, 0, stream>>>(qpk, kpk, vpk, x, xres);

    // 4. LN2 -> bf16 h
    ln_kernel<<<NROWS, 256, 0, stream>>>(xres, ln2_g, ln2_b, h_bf);

    // 5. FC1 + GELU -> bf16 mid (64x128 tiles, 8x96 = 768 blocks)
    mgemm128_kernel<1><<<dim3(HIDDEN_DIM / 128, NROWS / 64), 256, 0, stream>>>(
        h_bf, fc1_wt, fc1_b, (void*)mid, DIMC, HIDDEN_DIM);

    // 6. FC2 + residual -> f32 out (64x64)
    mgemm_kernel<2><<<dim3(DIMC / 64, NROWS / 64), 256, 0, stream>>>(
        mid, fc2_wt, fc2_b, xres, (void*)out, NROWS, HIDDEN_DIM, DIMC);
}